// Round 7
// baseline (87.091 us; speedup 1.0000x reference)
//
#include <hip/hip_runtime.h>
#include <math.h>

#define NN 10000
#define EE 640000
#define DD 256
#define HB 128            // hist/sort blocks; EE/HB = 5000 edges each
#define EPB (EE / HB)
#define CAP 128           // ELL row capacity (deg ~ Poisson(64); R4/R5 validated no overflow)
#define NTHR 512
#define RB 157            // 157*64 >= NN (reduce); also conv blocks: 157*8*8 = 10048 rows

// ws float-offset layout
#define OFF_DINV  0
#define OFF_XW    (NN)
#define OFF_C1    (2*NN)
#define OFF_C2    (3*NN)
#define OFF_CNT   (4*NN)            // int[NN]
#define OFF_XP    (5*NN)            // [0..143] xp1, [144] regAcc, [152] int done-ctr
#define OFF_CNTP  (5*NN + 160)      // int[HB*NN]
#define OFF_WDEGP (OFF_CNTP + HB*NN)  // float[HB*NN]
#define OFF_BASEP (OFF_WDEGP + HB*NN) // int[HB*NN]
#define OFF_SLOTS (OFF_BASEP + HB*NN) // uint2[NN*CAP] (even float offset -> 8B aligned)

// K1: blocks 0..HB-1: LDS histogram (count + weighted degree) of edge slice.
//     blocks HB..  : xw = x @ W1 (wave per row, prefetch). Block HB zeroes xp.
__global__ __launch_bounds__(NTHR) void k1_hist_xw(
    const int* __restrict__ dst, const float* __restrict__ ew,
    const float* __restrict__ x, const float* __restrict__ W1,
    float* __restrict__ ws)
{
    __shared__ int   s_cnt[NN];    // 40 KB
    __shared__ float s_wdeg[NN];   // 40 KB
    int tid = threadIdx.x, bid = blockIdx.x;
    if (bid < HB) {
        for (int i = tid; i < NN; i += NTHR) { s_cnt[i] = 0; s_wdeg[i] = 0.f; }
        __syncthreads();
        int base = bid * EPB;
        for (int k = tid; k < EPB; k += NTHR) {
            int e = base + k;
            int d = dst[e];
            atomicAdd(&s_cnt[d], 1);
            atomicAdd(&s_wdeg[d], ew[e]);
        }
        __syncthreads();
        int*   cp = (int*)ws + OFF_CNTP + bid * NN;
        float* wp = ws + OFF_WDEGP + bid * NN;
        for (int i = tid; i < NN; i += NTHR) { cp[i] = s_cnt[i]; wp[i] = s_wdeg[i]; }
    } else {
        if (bid == HB && tid < 160) ws[OFF_XP + tid] = 0.f;  // xp1+reg+done-ctr
        int lane = tid & 63, wv = tid >> 6;
        const int stride = (256 - HB) * 8;                   // 1024 waves
        float* xw = ws + OFF_XW;
        float4 wreg = reinterpret_cast<const float4*>(W1)[lane];
        int row = (bid - HB) * 8 + wv;
        if (row >= NN) return;
        float4 a = reinterpret_cast<const float4*>(x + (size_t)row * DD)[lane];
        while (true) {
            int nrow = row + stride;
            float4 an;
            if (nrow < NN) an = reinterpret_cast<const float4*>(x + (size_t)nrow * DD)[lane];
            float v = a.x*wreg.x + a.y*wreg.y + a.z*wreg.z + a.w*wreg.w;
            #pragma unroll
            for (int off = 32; off; off >>= 1) v += __shfl_xor(v, off);
            if (lane == 0) xw[row] = v;
            if (nrow >= NN) break;
            a = an; row = nrow;
        }
    }
}

// K2: per node (full chip, register-sliced): exclusive prefix over HB block
//     counts -> basep; total cnt; dinv = (1 + sum wdeg)^(-1/2).
//     Block: 64 nodes x 8 slices of 16 partials.
__global__ __launch_bounds__(NTHR) void k2_basep_dinv(float* __restrict__ ws)
{
    __shared__ int   red_c[8][64];
    __shared__ float red_w[8][64];
    int tid = threadIdx.x, bid = blockIdx.x;
    int nl = tid & 63, sl = tid >> 6;
    int node = bid * 64 + nl;
    const int*   cntp = (const int*)ws + OFF_CNTP;
    const float* wdp  = ws + OFF_WDEGP;
    int v[16];
    int csum = 0; float wsum = 0.f;
    if (node < NN) {
        #pragma unroll
        for (int t = 0; t < 16; ++t) {
            int b = sl * 16 + t;
            v[t] = cntp[(size_t)b * NN + node];
            csum += v[t];
            wsum += wdp[(size_t)b * NN + node];
        }
    }
    red_c[sl][nl] = csum;
    red_w[sl][nl] = wsum;
    __syncthreads();
    if (node < NN) {
        int pre = 0;
        for (int q = 0; q < sl; ++q) pre += red_c[q][nl];
        if (sl == 0) {
            int tot = 0; float wt = 1.f;              // self-loop weight 1
            #pragma unroll
            for (int q = 0; q < 8; ++q) { tot += red_c[q][nl]; wt += red_w[q][nl]; }
            ((int*)ws)[OFF_CNT + node] = min(tot, CAP);
            ws[OFF_DINV + node] = (wt > 0.f) ? 1.0f / sqrtf(wt) : 0.f;
        }
        int* basep = (int*)ws + OFF_BASEP;
        int run = pre;
        #pragma unroll
        for (int t = 0; t < 16; ++t) {
            basep[(size_t)(sl * 16 + t) * NN + node] = run;
            run += v[t];
        }
    }
}

// K3: rank-scatter edges into ELL slots, value = ew * dinv[src] * dinv[dst].
__global__ __launch_bounds__(NTHR) void k3_build(
    const int* __restrict__ src, const int* __restrict__ dst,
    const float* __restrict__ ew, float* __restrict__ ws)
{
    __shared__ int s_rank[NN];     // 40 KB
    int tid = threadIdx.x, bid = blockIdx.x;
    for (int i = tid; i < NN; i += NTHR) s_rank[i] = 0;
    __syncthreads();
    const float* dinv = ws + OFF_DINV;
    const int* basep = (const int*)ws + OFF_BASEP + (size_t)bid * NN;
    uint2* slots = (uint2*)(ws + OFF_SLOTS);
    int base = bid * EPB;
    for (int k = tid; k < EPB; k += NTHR) {
        int e = base + k;
        int d = dst[e], s = src[e];
        int r = atomicAdd(&s_rank[d], 1);
        int off = basep[d] + r;
        if (off < CAP) {
            uint2 pk;
            pk.x = (unsigned)s;
            pk.y = __float_as_uint(ew[e] * dinv[s] * dinv[d]);
            slots[(size_t)d * CAP + off] = pk;
        }
    }
}

// K4/K5: conv pass, wave per row (8 rows per wave):
//   c[i] = M * (sum_k w_k * h[src_k] + dinv^2 * h[i]) + B
__global__ __launch_bounds__(NTHR) void k_conv(
    const float* __restrict__ hin, float* __restrict__ cout,
    const float* __restrict__ multp, const float* __restrict__ biasp,
    float* __restrict__ ws)
{
    int tid = threadIdx.x, bid = blockIdx.x;
    int lane = tid & 63, wv = tid >> 6;
    const uint2* slots = (const uint2*)(ws + OFF_SLOTS);
    const int* cnt = (const int*)ws + OFF_CNT;
    const float* dinv = ws + OFF_DINV;
    float M = multp ? *multp : 1.0f;
    float B = *biasp;
    #pragma unroll
    for (int j = 0; j < 8; ++j) {
        int row = (bid * 8 + wv) * 8 + j;
        if (row >= NN) break;                 // wave-uniform
        int c = cnt[row];
        float acc = 0.f;
        for (int k = lane; k < c; k += 64) {
            uint2 pk = slots[(size_t)row * CAP + k];
            acc += __uint_as_float(pk.y) * hin[pk.x];
        }
        #pragma unroll
        for (int off = 32; off; off >>= 1) acc += __shfl_xor(acc, off);
        if (lane == 0) {
            float di = dinv[row];
            cout[row] = M * (acc + di * di * hin[row]) + B;
        }
    }
}

// K6: conv3 + pool stage 1 fused; last-done block runs pool stages 2..4.
__global__ __launch_bounds__(NTHR) void k6_final(
    const float* __restrict__ hin,                      // c2
    const float* __restrict__ multp, const float* __restrict__ biasp,
    const float* __restrict__ c1, const float* __restrict__ c2,
    const float* __restrict__ P1, const float* __restrict__ P2,
    const float* __restrict__ P3, float* __restrict__ ws, float* __restrict__ out)
{
    __shared__ float part[8][48][3];
    __shared__ float entW[8];
    __shared__ int sh_last;
    int tid = threadIdx.x, bid = blockIdx.x;
    int lane = tid & 63, wv = tid >> 6;
    const uint2* slots = (const uint2*)(ws + OFF_SLOTS);
    const int* cnt = (const int*)ws + OFF_CNT;
    const float* dinv = ws + OFF_DINV;
    float M = *multp, B = *biasp;
    float a0 = 0.f, a1 = 0.f, a2 = 0.f, ent = 0.f;
    #pragma unroll
    for (int j = 0; j < 8; ++j) {
        int row = (bid * 8 + wv) * 8 + j;
        if (row >= NN) break;                 // wave-uniform
        int c = cnt[row];
        float acc = 0.f;
        for (int k = lane; k < c; k += 64) {
            uint2 pk = slots[(size_t)row * CAP + k];
            acc += __uint_as_float(pk.y) * hin[pk.x];
        }
        #pragma unroll
        for (int off = 32; off; off >>= 1) acc += __shfl_xor(acc, off);
        float di = dinv[row];
        float cv = M * (acc + di * di * hin[row]) + B;   // c3[row], all lanes
        // pool stage 1 for this row
        float pv = (lane < 48) ? P1[(size_t)row * 48 + lane] : -1e30f;
        float mx = pv;
        #pragma unroll
        for (int off = 32; off; off >>= 1) mx = fmaxf(mx, __shfl_xor(mx, off));
        float e = (lane < 48) ? expf(pv - mx) : 0.f;
        float sum = e;
        #pragma unroll
        for (int off = 32; off; off >>= 1) sum += __shfl_xor(sum, off);
        float p = e / sum;
        if (lane < 48) {
            ent -= p * logf(p + 1e-12f);
            a0 += p * c1[row];
            a1 += p * c2[row];
            a2 += p * cv;
        }
    }
    #pragma unroll
    for (int off = 32; off; off >>= 1) ent += __shfl_xor(ent, off);
    if (lane == 0) entW[wv] = ent;
    if (lane < 48) { part[wv][lane][0] = a0; part[wv][lane][1] = a1; part[wv][lane][2] = a2; }
    __syncthreads();
    float* xp1 = ws + OFF_XP;
    if (tid < 144) {
        int j = tid / 3, col = tid % 3;
        float sp = 0.f;
        #pragma unroll
        for (int w = 0; w < 8; ++w) sp += part[w][j][col];
        atomicAdd(&xp1[j * 3 + col], sp);
    }
    if (tid == 0) {
        float sp = 0.f;
        #pragma unroll
        for (int w = 0; w < 8; ++w) sp += entW[w];
        atomicAdd(&xp1[144], sp);
    }
    // ---- last-block epilogue: pool stages 2..4 ----
    if (tid == 0) {
        __threadfence();
        int old = atomicAdd((int*)ws + OFF_XP + 152, 1);
        sh_last = (old == (int)gridDim.x - 1) ? 1 : 0;
    }
    __syncthreads();
    if (sh_last) {
        __shared__ float shXp[145];
        __shared__ float S2[48][12], xp2[12][3];
        __shared__ float S3[12][4], xp3[4][3];
        __shared__ float ent2, ent3;
        if (tid < 145) shXp[tid] = atomicAdd(&xp1[tid], 0.0f);  // coherent read
        if (tid == 0) { ent2 = 0.f; ent3 = 0.f; }
        __syncthreads();
        if (tid < 48) {
            float v[12], mx = -1e30f;
            #pragma unroll
            for (int j = 0; j < 12; j++) { v[j] = P2[tid * 12 + j]; mx = fmaxf(mx, v[j]); }
            float sm = 0.f;
            #pragma unroll
            for (int j = 0; j < 12; j++) { v[j] = expf(v[j] - mx); sm += v[j]; }
            float e = 0.f;
            #pragma unroll
            for (int j = 0; j < 12; j++) {
                float p = v[j] / sm; S2[tid][j] = p; e -= p * logf(p + 1e-12f);
            }
            atomicAdd(&ent2, e);
        }
        __syncthreads();
        if (tid < 36) {
            int j = tid / 3, col = tid % 3;
            float sm = 0.f;
            for (int i = 0; i < 48; i++) sm += S2[i][j] * shXp[i * 3 + col];
            xp2[j][col] = sm;
        }
        __syncthreads();
        if (tid < 12) {
            float v[4], mx = -1e30f;
            #pragma unroll
            for (int j = 0; j < 4; j++) { v[j] = P3[tid * 4 + j]; mx = fmaxf(mx, v[j]); }
            float sm = 0.f;
            #pragma unroll
            for (int j = 0; j < 4; j++) { v[j] = expf(v[j] - mx); sm += v[j]; }
            float e = 0.f;
            #pragma unroll
            for (int j = 0; j < 4; j++) {
                float p = v[j] / sm; S3[tid][j] = p; e -= p * logf(p + 1e-12f);
            }
            atomicAdd(&ent3, e);
        }
        __syncthreads();
        if (tid < 12) {
            int j = tid / 3, col = tid % 3;
            float sm = 0.f;
            for (int i = 0; i < 12; i++) sm += S3[i][j] * xp2[i][col];
            xp3[j][col] = sm;
        }
        __syncthreads();
        if (tid == 0) {
            float o0 = 0.f, o1 = 0.f, o2 = 0.f;
            for (int i = 0; i < 4; i++) {
                o0 += xp3[i][0]; o1 += xp3[i][1]; o2 += xp3[i][2];
            }
            // stage-4: width-1 softmax -> p==1, entropy==0 in fp32
            float reg = shXp[144] / (float)NN + ent2 / 48.f + ent3 / 12.f;
            out[0] = o0; out[1] = o1; out[2] = o2; out[3] = reg;
        }
    }
}

extern "C" void kernel_launch(void* const* d_in, const int* in_sizes, int n_in,
                              void* d_out, int out_size, void* d_ws, size_t ws_size,
                              hipStream_t stream) {
    const float* x  = (const float*)d_in[0];
    const int*   ei = (const int*)d_in[1];
    const float* ea = (const float*)d_in[2];
    // d_in[3] = adj — unused by the reference.
    const float* W1 = (const float*)d_in[4];
    const float* b1 = (const float*)d_in[5];
    const float* W2 = (const float*)d_in[6];
    const float* b2 = (const float*)d_in[7];
    const float* P1 = (const float*)d_in[8];
    const float* P2 = (const float*)d_in[9];
    const float* P3 = (const float*)d_in[10];
    // d_in[11] = P4 — width-1 softmax, handled analytically.
    const int* src = ei;
    const int* dst = ei + EE;
    float* ws  = (float*)d_ws;
    float* out = (float*)d_out;

    float* xw = ws + OFF_XW;
    float* c1 = ws + OFF_C1;
    float* c2 = ws + OFF_C2;

    k1_hist_xw<<<256, NTHR, 0, stream>>>(dst, ea, x, W1, ws);
    k2_basep_dinv<<<RB, NTHR, 0, stream>>>(ws);
    k3_build<<<HB, NTHR, 0, stream>>>(src, dst, ea, ws);
    k_conv<<<RB, NTHR, 0, stream>>>(xw, c1, nullptr, b1, ws);
    k_conv<<<RB, NTHR, 0, stream>>>(c1, c2, W2, b2, ws);
    k6_final<<<RB, NTHR, 0, stream>>>(c2, W2, b2, c1, c2, P1, P2, P3, ws, out);
}